// Round 1
// baseline (653.599 us; speedup 1.0000x reference)
//
#include <hip/hip_runtime.h>
#include <hip/hip_bf16.h>

#define DD 128
#define HH 128
#define NATOMS 512
#define NK 1536  // 3*N

// ---------------- Kernel 1: per-atom MLP forward + input gradient ----------------
__global__ __launch_bounds__(128) void mlp_grad_kernel(
    const float* __restrict__ desc,    // [N,D]
    const float* __restrict__ W0,      // [S,H,D]
    const float* __restrict__ b0,      // [S,H]
    const float* __restrict__ W1,      // [S,H,H]
    const float* __restrict__ b1,      // [S,H]
    const float* __restrict__ W2,      // [S,1,H]
    const float* __restrict__ b2,      // [S,1]
    const int*   __restrict__ species, // [N]
    float* __restrict__ G,             // ws [N,D]
    float* __restrict__ E)             // ws [N]
{
    const int i = blockIdx.x;
    const int t = threadIdx.x;
    __shared__ float s_desc[128];
    __shared__ float s_h0[128];
    __shared__ float s_d1[128];
    __shared__ float s_d0[128];
    __shared__ float s_red[2];

    const int sp = species[i];
    const float* w0 = W0 + sp * 128 * 128;
    const float* w1 = W1 + sp * 128 * 128;
    const float* w2 = W2 + sp * 128;

    s_desc[t] = desc[i * 128 + t];
    __syncthreads();

    // h0[t] = tanh(w0[t,:] . desc + b0[t])
    float acc = b0[sp * 128 + t];
    {
        const float* row = w0 + t * 128;
        #pragma unroll 8
        for (int d = 0; d < 128; ++d) acc += row[d] * s_desc[d];
    }
    const float h0 = tanhf(acc);
    s_h0[t] = h0;
    __syncthreads();

    // h1[t] = tanh(w1[t,:] . h0 + b1[t])
    acc = b1[sp * 128 + t];
    {
        const float* row = w1 + t * 128;
        #pragma unroll 8
        for (int d = 0; d < 128; ++d) acc += row[d] * s_h0[d];
    }
    const float h1 = tanhf(acc);

    // energy partial + d1
    const float w2t = w2[t];
    float ep = w2t * h1;
    #pragma unroll
    for (int o = 32; o > 0; o >>= 1) ep += __shfl_down(ep, o, 64);
    if ((t & 63) == 0) s_red[t >> 6] = ep;

    const float d1 = (1.f - h1 * h1) * w2t;
    s_d1[t] = d1;
    __syncthreads();
    if (t == 0) E[i] = s_red[0] + s_red[1] + b2[sp];

    // dh0[t] = sum_k w1[k,t] * d1[k]  (coalesced across t)
    acc = 0.f;
    #pragma unroll 8
    for (int k = 0; k < 128; ++k) acc += w1[k * 128 + t] * s_d1[k];
    const float d0 = (1.f - h0 * h0) * acc;
    s_d0[t] = d0;
    __syncthreads();

    // G[i,t] = sum_j w0[j,t] * d0[j]  (coalesced across t)
    acc = 0.f;
    #pragma unroll 8
    for (int j = 0; j < 128; ++j) acc += w0[j * 128 + t] * s_d0[j];
    G[i * 128 + t] = acc;
}

// ---------------- Kernel 2: forces partials (the 402 MB stream) ----------------
// Block: 256 threads = 4 waves. Each block handles 8 consecutive k's (4 k-pairs,
// one per wave) over a 64-atom i-chunk. grid = 192 k-groups * 8 i-chunks.
__global__ __launch_bounds__(256) void forces_kernel(
    const float* __restrict__ CG,      // [N, NK, D]
    const float* __restrict__ G,       // [N, D]
    float* __restrict__ partial)       // [8, NK]
{
    const int kg   = blockIdx.x % 192;
    const int ic   = blockIdx.x / 192;
    const int t    = threadIdx.x;
    const int wave = t >> 6;
    const int lane = t & 63;

    __shared__ float s_G[64 * 128];  // 32 KB

    const int i0 = ic * 64;
    {   // cooperative G-chunk load: 8192 floats, float4-vectorized
        const float4* Gv  = (const float4*)(G + (size_t)i0 * 128);
        float4*       sGv = (float4*)s_G;
        #pragma unroll
        for (int r = 0; r < 8; ++r) sGv[r * 256 + t] = Gv[r * 256 + t];
    }
    __syncthreads();

    const int k0   = kg * 8 + wave * 2;   // this wave: k0 (lanes 0-31), k0+1 (lanes 32-63)
    const int half = lane >> 5;
    const int l5   = lane & 31;
    const int off  = half * 128 + l5 * 4;

    const float* cgbase = CG + (size_t)i0 * NK * DD + (size_t)k0 * DD + off;
    float acc = 0.f;
    #pragma unroll 4
    for (int i = 0; i < 64; ++i) {
        const float4 cg = *(const float4*)(cgbase + (size_t)i * (NK * DD));
        const float4 g  = *(const float4*)(s_G + i * 128 + l5 * 4);
        acc += cg.x * g.x + cg.y * g.y + cg.z * g.z + cg.w * g.w;
    }
    // reduce within each 32-lane half (xor offsets < 32 stay in-half)
    #pragma unroll
    for (int o = 16; o > 0; o >>= 1) acc += __shfl_xor(acc, o, 64);
    if (l5 == 0) partial[ic * NK + k0 + half] = acc;
}

// ---------------- Kernel 3: finalize (forces reduce, stress, energy sum) --------
__global__ __launch_bounds__(256) void finalize_kernel(
    const float* __restrict__ partial, // [8, NK]
    const float* __restrict__ E,       // [N]
    const float* __restrict__ SG,      // [N,6,D]
    const float* __restrict__ G,       // [N,D]
    const float* __restrict__ volume,  // [1]
    float* __restrict__ out)           // [1543]
{
    const int b = blockIdx.x;
    const int t = threadIdx.x;
    __shared__ float red[4];

    if (b < 6) {
        // forces: out[1+k] = sum_c partial[c][k]
        const int k = b * 256 + t;
        float f = 0.f;
        #pragma unroll
        for (int c = 0; c < 8; ++c) f += partial[c * NK + k];
        out[1 + k] = f;
    } else if (b < 12) {
        // stress component s
        const int s = b - 6;
        const int d = t & 127;
        const int ih = t >> 7;
        float acc = 0.f;
        for (int i = ih; i < NATOMS; i += 2)
            acc += SG[((size_t)i * 6 + s) * 128 + d] * G[i * 128 + d];
        #pragma unroll
        for (int o = 32; o > 0; o >>= 1) acc += __shfl_down(acc, o, 64);
        if ((t & 63) == 0) red[t >> 6] = acc;
        __syncthreads();
        if (t == 0) out[1537 + s] = -(red[0] + red[1] + red[2] + red[3]) / volume[0];
    } else {
        // energy sum over 512 atoms
        float acc = E[t] + E[t + 256];
        #pragma unroll
        for (int o = 32; o > 0; o >>= 1) acc += __shfl_down(acc, o, 64);
        if ((t & 63) == 0) red[t >> 6] = acc;
        __syncthreads();
        if (t == 0) out[0] = red[0] + red[1] + red[2] + red[3];
    }
}

extern "C" void kernel_launch(void* const* d_in, const int* in_sizes, int n_in,
                              void* d_out, int out_size, void* d_ws, size_t ws_size,
                              hipStream_t stream) {
    const float* desc    = (const float*)d_in[0];
    const float* CG      = (const float*)d_in[1];
    const float* SG      = (const float*)d_in[2];
    const float* W0      = (const float*)d_in[3];
    const float* b0      = (const float*)d_in[4];
    const float* W1      = (const float*)d_in[5];
    const float* b1      = (const float*)d_in[6];
    const float* W2      = (const float*)d_in[7];
    const float* b2      = (const float*)d_in[8];
    const float* vol     = (const float*)d_in[9];
    const int*   species = (const int*)d_in[10];
    float* out = (float*)d_out;

    float* G       = (float*)d_ws;        // 512*128
    float* E       = G + 512 * 128;       // 512
    float* partial = E + 512;             // 8*1536

    mlp_grad_kernel<<<NATOMS, 128, 0, stream>>>(desc, W0, b0, W1, b1, W2, b2, species, G, E);
    forces_kernel<<<192 * 8, 256, 0, stream>>>(CG, G, partial);
    finalize_kernel<<<13, 256, 0, stream>>>(partial, E, SG, G, vol, out);
}